// Round 3
// baseline (241.526 us; speedup 1.0000x reference)
//
#include <hip/hip_runtime.h>
#include <cmath>

namespace {
constexpr int NB  = 256;   // batch
constexpr int CI  = 64;    // in channels
constexpr int CO  = 64;    // out channels
constexpr int TT  = 64;    // time
constexpr int V   = 25;    // vertices
constexpr int VP  = 28;    // padded V (16B-aligned LDS rows)
constexpr int REL = 8;     // rel channels
constexpr int TV  = TT * V;   // 1600
constexpr int CCB = 8;     // channels per k2b block
}

typedef float f4 __attribute__((ext_vector_type(4)));
struct __attribute__((packed, aligned(4))) F4u { float x, y, z, w; };  // 4B-aligned 16B load

// ---------------------------------------------------------------------------
// K1: per-n temporal reduction -> x1,x2 (REL*V each) into ws. (unchanged)
// ---------------------------------------------------------------------------
__global__ __launch_bounds__(1024) void k1_x12(
    const float* __restrict__ x,
    const float* __restrict__ w1, const float* __restrict__ b1,
    const float* __restrict__ w2, const float* __restrict__ b2,
    float* __restrict__ ws) {
  const int n = blockIdx.x;
  const int tid = threadIdx.x;
  __shared__ __align__(16) float xs[8][TV];
  __shared__ float xsum[CI][V];
  __shared__ float w12[2][REL][CI];

  for (int idx = tid; idx < 2 * REL * CI; idx += 1024) {
    int half = idx / (REL * CI), rem = idx % (REL * CI);
    w12[half][rem / CI][rem % CI] = half ? w2[rem] : w1[rem];
  }

  const float4* xb = reinterpret_cast<const float4*>(x + (size_t)n * (CI * TV));
  float4* xsv = reinterpret_cast<float4*>(&xs[0][0]);
  constexpr int V4G = 8 * TV / 4;  // 3200

  for (int g = 0; g < 8; ++g) {
    __syncthreads();
    for (int idx = tid; idx < V4G; idx += 1024)
      xsv[idx] = xb[g * V4G + idx];
    __syncthreads();
    if (tid < 8 * V) {
      int ch = tid / V, v = tid % V;
      float acc = 0.f;
      #pragma unroll
      for (int t = 0; t < TT; ++t) acc += xs[ch][t * V + v];
      xsum[g * 8 + ch][v] = acc;
    }
  }
  __syncthreads();

  if (tid < 2 * REL * V) {
    int half = tid / (REL * V), rem = tid % (REL * V);
    int r = rem / V, v = rem % V;
    float a = 0.f;
    #pragma unroll
    for (int i = 0; i < CI; ++i) a = fmaf(w12[half][r][i], xsum[i][v], a);
    ws[(size_t)n * (2 * REL * V) + tid] = a * (1.f / TT) + (half ? b2[r] : b1[r]);
  }
}

// ---------------------------------------------------------------------------
// K2a: inputs[n,c,t,v] = sum_i wr[c,i] x[n,i,t,v] + br[c], written into d_out.
// Thread = flat (n,tv); all 64 c in registers; wr/br via wave-uniform s_loads.
// No LDS, no barriers. Grid = 409600/256 = 1600 blocks.
// ---------------------------------------------------------------------------
__global__ __launch_bounds__(256) void k2a_inputs(
    const float* __restrict__ x, const float* __restrict__ wr,
    const float* __restrict__ br, float* __restrict__ io) {
  const int idx = blockIdx.x * 256 + threadIdx.x;   // 0..409599
  const int n  = idx / TV;
  const int tv = idx - n * TV;
  const float* xp = x + (size_t)n * (CI * TV) + tv;

  float acc[CO];
  #pragma unroll
  for (int c = 0; c < CO; ++c) acc[c] = br[c];      // uniform -> s_load

  #pragma unroll 8
  for (int i = 0; i < CI; ++i) {
    float xv = xp[(size_t)i * TV];                  // coalesced 256B/wave
    #pragma unroll
    for (int c = 0; c < CO; ++c)
      acc[c] = fmaf(wr[c * CI + i], xv, acc[c]);    // uniform addr -> s_load
  }

  float* op = io + (size_t)n * (CO * TV) + tv;
  #pragma unroll
  for (int c = 0; c < CO; ++c) op[(size_t)c * TV] = acc[c];  // coalesced
}

// ---------------------------------------------------------------------------
// K2b: out[n,c,t,u] = sum_v Af[n,c,u,v] * inputs[n,c,t,v], in place in d_out.
// Block = (cb of 8 c, n), 256 thr. LDS: d[8][25][28] + Af[8][25][28].
// Thread = (cc, tt) owns private rows t=tt and t=tt+32 -> race-free in-place.
// ---------------------------------------------------------------------------
__global__ __launch_bounds__(256) void k2b_graph(
    const float* __restrict__ A, const float* __restrict__ w3,
    const float* __restrict__ b3, const float* __restrict__ ws,
    float* __restrict__ io) {
  const int cb  = blockIdx.x;          // 0..7
  const int n   = blockIdx.y;          // 0..255
  const int tid = threadIdx.x;         // 0..255
  const int c0  = cb * CCB;

  __shared__ __align__(16) float dl[REL * V * VP];   // 22.4 KB
  __shared__ __align__(16) float Afs[CCB * V * VP];  // 22.4 KB

  const float* x1n = ws + (size_t)n * (2 * REL * V);
  const float* x2n = x1n + REL * V;

  // d[r][u][v] = tanh(x1[r][u] - x2[r][v])
  for (int idx = tid; idx < REL * V * V; idx += 256) {
    int r = idx / (V * V), rem = idx % (V * V);
    int u = rem / V, v = rem % V;
    dl[(r * V + u) * VP + v] = tanhf(x1n[r * V + u] - x2n[r * V + v]);
  }
  __syncthreads();

  // Af[cc][u][v] = A[u][v] + b3[c] + sum_r w3[c][r] * d[r][u][v]
  for (int idx = tid; idx < CCB * V * V; idx += 256) {
    int cc = idx / (V * V), rem = idx % (V * V);
    int u = rem / V, v = rem % V;
    float acc = A[rem] + b3[c0 + cc];
    #pragma unroll
    for (int r = 0; r < REL; ++r)
      acc = fmaf(w3[(c0 + cc) * REL + r], dl[(r * V + u) * VP + v], acc);
    Afs[(cc * V + u) * VP + v] = acc;
  }
  __syncthreads();

  // main loop: no more barriers, fully thread-private
  const int cc = tid >> 5;             // 0..7
  const int tt = tid & 31;             // 0..31
  const int c  = c0 + cc;

  float* row0 = io + (((size_t)n * CO + c) * TT + tt) * V;
  float* row1 = row0 + 32 * V;

  float in0[V], in1[V];
  {
    const F4u* p0 = reinterpret_cast<const F4u*>(row0);
    const F4u* p1 = reinterpret_cast<const F4u*>(row1);
    #pragma unroll
    for (int g = 0; g < 6; ++g) {
      F4u a = p0[g]; F4u b = p1[g];
      in0[4*g+0] = a.x; in0[4*g+1] = a.y; in0[4*g+2] = a.z; in0[4*g+3] = a.w;
      in1[4*g+0] = b.x; in1[4*g+1] = b.y; in1[4*g+2] = b.z; in1[4*g+3] = b.w;
    }
    in0[24] = row0[24];
    in1[24] = row1[24];
  }

  const f4* afrow = reinterpret_cast<const f4*>(Afs + cc * (V * VP));
  #pragma unroll
  for (int u = 0; u < V; ++u) {
    const f4* ar = afrow + u * (VP / 4);
    f4 b0 = ar[0], b1 = ar[1], b2 = ar[2], b3v = ar[3],
       b4 = ar[4], b5 = ar[5], b6 = ar[6];

    float s0, s1, s2, s3, r0, r1, r2, r3;
    s0 = b0.x * in0[0];  s1 = b0.y * in0[1];  s2 = b0.z * in0[2];  s3 = b0.w * in0[3];
    r0 = b0.x * in1[0];  r1 = b0.y * in1[1];  r2 = b0.z * in1[2];  r3 = b0.w * in1[3];
    s0 = fmaf(b1.x, in0[4], s0);   s1 = fmaf(b1.y, in0[5], s1);
    s2 = fmaf(b1.z, in0[6], s2);   s3 = fmaf(b1.w, in0[7], s3);
    r0 = fmaf(b1.x, in1[4], r0);   r1 = fmaf(b1.y, in1[5], r1);
    r2 = fmaf(b1.z, in1[6], r2);   r3 = fmaf(b1.w, in1[7], r3);
    s0 = fmaf(b2.x, in0[8], s0);   s1 = fmaf(b2.y, in0[9], s1);
    s2 = fmaf(b2.z, in0[10], s2);  s3 = fmaf(b2.w, in0[11], s3);
    r0 = fmaf(b2.x, in1[8], r0);   r1 = fmaf(b2.y, in1[9], r1);
    r2 = fmaf(b2.z, in1[10], r2);  r3 = fmaf(b2.w, in1[11], r3);
    s0 = fmaf(b3v.x, in0[12], s0); s1 = fmaf(b3v.y, in0[13], s1);
    s2 = fmaf(b3v.z, in0[14], s2); s3 = fmaf(b3v.w, in0[15], s3);
    r0 = fmaf(b3v.x, in1[12], r0); r1 = fmaf(b3v.y, in1[13], r1);
    r2 = fmaf(b3v.z, in1[14], r2); r3 = fmaf(b3v.w, in1[15], r3);
    s0 = fmaf(b4.x, in0[16], s0);  s1 = fmaf(b4.y, in0[17], s1);
    s2 = fmaf(b4.z, in0[18], s2);  s3 = fmaf(b4.w, in0[19], s3);
    r0 = fmaf(b4.x, in1[16], r0);  r1 = fmaf(b4.y, in1[17], r1);
    r2 = fmaf(b4.z, in1[18], r2);  r3 = fmaf(b4.w, in1[19], r3);
    s0 = fmaf(b5.x, in0[20], s0);  s1 = fmaf(b5.y, in0[21], s1);
    s2 = fmaf(b5.z, in0[22], s2);  s3 = fmaf(b5.w, in0[23], s3);
    r0 = fmaf(b5.x, in1[20], r0);  r1 = fmaf(b5.y, in1[21], r1);
    r2 = fmaf(b5.z, in1[22], r2);  r3 = fmaf(b5.w, in1[23], r3);
    s0 = fmaf(b6.x, in0[24], s0);
    r0 = fmaf(b6.x, in1[24], r0);

    row0[u] = (s0 + s1) + (s2 + s3);   // in0/in1 fully in regs: in-place safe
    row1[u] = (r0 + r1) + (r2 + r3);
  }
}

extern "C" void kernel_launch(void* const* d_in, const int* in_sizes, int n_in,
                              void* d_out, int out_size, void* d_ws, size_t ws_size,
                              hipStream_t stream) {
  (void)in_sizes; (void)n_in; (void)out_size; (void)ws_size;
  const float* x  = (const float*)d_in[0];
  const float* A  = (const float*)d_in[1];
  const float* w1 = (const float*)d_in[2];
  const float* b1 = (const float*)d_in[3];
  const float* w2 = (const float*)d_in[4];
  const float* b2 = (const float*)d_in[5];
  const float* w3 = (const float*)d_in[6];
  const float* b3 = (const float*)d_in[7];
  const float* wr = (const float*)d_in[8];
  const float* br = (const float*)d_in[9];
  float* out = (float*)d_out;
  float* ws  = (float*)d_ws;

  hipLaunchKernelGGL(k1_x12, dim3(NB), dim3(1024), 0, stream,
                     x, w1, b1, w2, b2, ws);
  hipLaunchKernelGGL(k2a_inputs, dim3(NB * TV / 256), dim3(256), 0, stream,
                     x, wr, br, out);
  hipLaunchKernelGGL(k2b_graph, dim3(CO / CCB, NB), dim3(256), 0, stream,
                     A, w3, b3, ws, out);
}

// Round 4
// 176.348 us; speedup vs baseline: 1.3696x; 1.3696x over previous
//
#include <hip/hip_runtime.h>
#include <cmath>

namespace {
constexpr int NB  = 256;   // batch
constexpr int CI  = 64;    // in channels
constexpr int CO  = 64;    // out channels
constexpr int TT  = 64;    // time
constexpr int V   = 25;    // vertices
constexpr int VP  = 28;    // padded V (16B-aligned LDS rows)
constexpr int REL = 8;     // rel channels
constexpr int TV  = TT * V;   // 1600
constexpr int CCB = 8;     // channels per k2b block
constexpr int CCH = 16;    // channel chunk per k2a pass
}

typedef float f4 __attribute__((ext_vector_type(4)));
struct __attribute__((packed, aligned(4))) F4u { float x, y, z, w; };  // 4B-aligned 16B load

// ---------------------------------------------------------------------------
// K1: per-n temporal reduction -> x1,x2 (REL*V each) into ws. (unchanged)
// ---------------------------------------------------------------------------
__global__ __launch_bounds__(1024) void k1_x12(
    const float* __restrict__ x,
    const float* __restrict__ w1, const float* __restrict__ b1,
    const float* __restrict__ w2, const float* __restrict__ b2,
    float* __restrict__ ws) {
  const int n = blockIdx.x;
  const int tid = threadIdx.x;
  __shared__ __align__(16) float xs[8][TV];
  __shared__ float xsum[CI][V];
  __shared__ float w12[2][REL][CI];

  for (int idx = tid; idx < 2 * REL * CI; idx += 1024) {
    int half = idx / (REL * CI), rem = idx % (REL * CI);
    w12[half][rem / CI][rem % CI] = half ? w2[rem] : w1[rem];
  }

  const float4* xb = reinterpret_cast<const float4*>(x + (size_t)n * (CI * TV));
  float4* xsv = reinterpret_cast<float4*>(&xs[0][0]);
  constexpr int V4G = 8 * TV / 4;  // 3200

  for (int g = 0; g < 8; ++g) {
    __syncthreads();
    for (int idx = tid; idx < V4G; idx += 1024)
      xsv[idx] = xb[g * V4G + idx];
    __syncthreads();
    if (tid < 8 * V) {
      int ch = tid / V, v = tid % V;
      float acc = 0.f;
      #pragma unroll
      for (int t = 0; t < TT; ++t) acc += xs[ch][t * V + v];
      xsum[g * 8 + ch][v] = acc;
    }
  }
  __syncthreads();

  if (tid < 2 * REL * V) {
    int half = tid / (REL * V), rem = tid % (REL * V);
    int r = rem / V, v = rem % V;
    float a = 0.f;
    #pragma unroll
    for (int i = 0; i < CI; ++i) a = fmaf(w12[half][r][i], xsum[i][v], a);
    ws[(size_t)n * (2 * REL * V) + tid] = a * (1.f / TT) + (half ? b2[r] : b1[r]);
  }
}

// ---------------------------------------------------------------------------
// K2a: inputs[n,c,t,v] = sum_i wr[c,i] x[n,i,t,v] + br[c] -> written to d_out.
// Thread = 2 consecutive tv; channels in 4 chunks of 16 (32 acc VGPRs, no
// spill). wr/br via wave-uniform s_loads; x re-reads are L2-resident.
// ---------------------------------------------------------------------------
__global__ __launch_bounds__(256, 2) void k2a_inputs(
    const float* __restrict__ x, const float* __restrict__ wr,
    const float* __restrict__ br, float* __restrict__ io) {
  const int gid = blockIdx.x * 256 + threadIdx.x;   // 0..204799
  const int n   = gid / (TV / 2);
  const int tv  = (gid - n * (TV / 2)) * 2;
  const float* xp = x + (size_t)n * (CI * TV) + tv;
  float* op       = io + (size_t)n * (CO * TV) + tv;

  #pragma unroll
  for (int c0 = 0; c0 < CO; c0 += CCH) {
    float ax[CCH], ay[CCH];
    #pragma unroll
    for (int cc = 0; cc < CCH; ++cc) { ax[cc] = br[c0 + cc]; ay[cc] = ax[cc]; }

    #pragma unroll 4
    for (int i = 0; i < CI; ++i) {
      float2 xv = *reinterpret_cast<const float2*>(xp + (size_t)i * TV);
      #pragma unroll
      for (int cc = 0; cc < CCH; ++cc) {
        float w = wr[(c0 + cc) * CI + i];        // uniform -> s_load
        ax[cc] = fmaf(w, xv.x, ax[cc]);
        ay[cc] = fmaf(w, xv.y, ay[cc]);
      }
    }

    #pragma unroll
    for (int cc = 0; cc < CCH; ++cc) {
      float2 o; o.x = ax[cc]; o.y = ay[cc];
      *reinterpret_cast<float2*>(op + (size_t)(c0 + cc) * TV) = o;  // coalesced
    }
  }
}

// ---------------------------------------------------------------------------
// K2b: out[n,c,t,u] = sum_v Af[n,c,u,v] * inputs[n,c,t,v], in place in d_out.
// Block = (cb of 8 c, n), 256 thr. LDS: Af only (22.4 KB) -- tanh folded
// directly into the Af build, no d buffer. Main loop barrier-free,
// thread-private rows t=tt and t=tt+32 -> race-free in-place.
// ---------------------------------------------------------------------------
__global__ __launch_bounds__(256) void k2b_graph(
    const float* __restrict__ A, const float* __restrict__ w3,
    const float* __restrict__ b3, const float* __restrict__ ws,
    float* __restrict__ io) {
  const int cb  = blockIdx.x;          // 0..7
  const int n   = blockIdx.y;          // 0..255
  const int tid = threadIdx.x;         // 0..255
  const int c0  = cb * CCB;

  __shared__ __align__(16) float Afs[CCB * V * VP];  // 22.4 KB

  const float* x1n = ws + (size_t)n * (2 * REL * V);
  const float* x2n = x1n + REL * V;

  // Af[cc][u][v] = A[u][v] + b3[c] + sum_r w3[c][r] * tanh(x1[r][u]-x2[r][v])
  for (int idx = tid; idx < V * V; idx += 256) {
    int u = idx / V, v = idx % V;
    float t8[REL];
    #pragma unroll
    for (int r = 0; r < REL; ++r)
      t8[r] = tanhf(x1n[r * V + u] - x2n[r * V + v]);
    const float base = A[idx];
    #pragma unroll
    for (int cc = 0; cc < CCB; ++cc) {
      float acc = base + b3[c0 + cc];             // uniform -> s_load
      #pragma unroll
      for (int r = 0; r < REL; ++r)
        acc = fmaf(w3[(c0 + cc) * REL + r], t8[r], acc);  // uniform -> s_load
      Afs[(cc * V + u) * VP + v] = acc;
    }
  }
  __syncthreads();

  // main loop: barrier-free, fully thread-private
  const int cc = tid >> 5;             // 0..7
  const int tt = tid & 31;             // 0..31
  const int c  = c0 + cc;

  float* row0 = io + (((size_t)n * CO + c) * TT + tt) * V;
  float* row1 = row0 + 32 * V;

  float in0[V], in1[V];
  {
    const F4u* p0 = reinterpret_cast<const F4u*>(row0);
    const F4u* p1 = reinterpret_cast<const F4u*>(row1);
    #pragma unroll
    for (int g = 0; g < 6; ++g) {
      F4u a = p0[g]; F4u b = p1[g];
      in0[4*g+0] = a.x; in0[4*g+1] = a.y; in0[4*g+2] = a.z; in0[4*g+3] = a.w;
      in1[4*g+0] = b.x; in1[4*g+1] = b.y; in1[4*g+2] = b.z; in1[4*g+3] = b.w;
    }
    in0[24] = row0[24];
    in1[24] = row1[24];
  }

  const f4* afrow = reinterpret_cast<const f4*>(Afs + cc * (V * VP));
  #pragma unroll
  for (int u = 0; u < V; ++u) {
    const f4* ar = afrow + u * (VP / 4);
    f4 b0 = ar[0], b1 = ar[1], b2 = ar[2], b3v = ar[3],
       b4 = ar[4], b5 = ar[5], b6 = ar[6];

    float s0, s1, s2, s3, r0, r1, r2, r3;
    s0 = b0.x * in0[0];  s1 = b0.y * in0[1];  s2 = b0.z * in0[2];  s3 = b0.w * in0[3];
    r0 = b0.x * in1[0];  r1 = b0.y * in1[1];  r2 = b0.z * in1[2];  r3 = b0.w * in1[3];
    s0 = fmaf(b1.x, in0[4], s0);   s1 = fmaf(b1.y, in0[5], s1);
    s2 = fmaf(b1.z, in0[6], s2);   s3 = fmaf(b1.w, in0[7], s3);
    r0 = fmaf(b1.x, in1[4], r0);   r1 = fmaf(b1.y, in1[5], r1);
    r2 = fmaf(b1.z, in1[6], r2);   r3 = fmaf(b1.w, in1[7], r3);
    s0 = fmaf(b2.x, in0[8], s0);   s1 = fmaf(b2.y, in0[9], s1);
    s2 = fmaf(b2.z, in0[10], s2);  s3 = fmaf(b2.w, in0[11], s3);
    r0 = fmaf(b2.x, in1[8], r0);   r1 = fmaf(b2.y, in1[9], r1);
    r2 = fmaf(b2.z, in1[10], r2);  r3 = fmaf(b2.w, in1[11], r3);
    s0 = fmaf(b3v.x, in0[12], s0); s1 = fmaf(b3v.y, in0[13], s1);
    s2 = fmaf(b3v.z, in0[14], s2); s3 = fmaf(b3v.w, in0[15], s3);
    r0 = fmaf(b3v.x, in1[12], r0); r1 = fmaf(b3v.y, in1[13], r1);
    r2 = fmaf(b3v.z, in1[14], r2); r3 = fmaf(b3v.w, in1[15], r3);
    s0 = fmaf(b4.x, in0[16], s0);  s1 = fmaf(b4.y, in0[17], s1);
    s2 = fmaf(b4.z, in0[18], s2);  s3 = fmaf(b4.w, in0[19], s3);
    r0 = fmaf(b4.x, in1[16], r0);  r1 = fmaf(b4.y, in1[17], r1);
    r2 = fmaf(b4.z, in1[18], r2);  r3 = fmaf(b4.w, in1[19], r3);
    s0 = fmaf(b5.x, in0[20], s0);  s1 = fmaf(b5.y, in0[21], s1);
    s2 = fmaf(b5.z, in0[22], s2);  s3 = fmaf(b5.w, in0[23], s3);
    r0 = fmaf(b5.x, in1[20], r0);  r1 = fmaf(b5.y, in1[21], r1);
    r2 = fmaf(b5.z, in1[22], r2);  r3 = fmaf(b5.w, in1[23], r3);
    s0 = fmaf(b6.x, in0[24], s0);
    r0 = fmaf(b6.x, in1[24], r0);

    row0[u] = (s0 + s1) + (s2 + s3);   // in0/in1 fully in regs: in-place safe
    row1[u] = (r0 + r1) + (r2 + r3);
  }
}

extern "C" void kernel_launch(void* const* d_in, const int* in_sizes, int n_in,
                              void* d_out, int out_size, void* d_ws, size_t ws_size,
                              hipStream_t stream) {
  (void)in_sizes; (void)n_in; (void)out_size; (void)ws_size;
  const float* x  = (const float*)d_in[0];
  const float* A  = (const float*)d_in[1];
  const float* w1 = (const float*)d_in[2];
  const float* b1 = (const float*)d_in[3];
  const float* w2 = (const float*)d_in[4];
  const float* b2 = (const float*)d_in[5];
  const float* w3 = (const float*)d_in[6];
  const float* b3 = (const float*)d_in[7];
  const float* wr = (const float*)d_in[8];
  const float* br = (const float*)d_in[9];
  float* out = (float*)d_out;
  float* ws  = (float*)d_ws;

  hipLaunchKernelGGL(k1_x12, dim3(NB), dim3(1024), 0, stream,
                     x, w1, b1, w2, b2, ws);
  hipLaunchKernelGGL(k2a_inputs, dim3(NB * TV / 2 / 256), dim3(256), 0, stream,
                     x, wr, br, out);
  hipLaunchKernelGGL(k2b_graph, dim3(CO / CCB, NB), dim3(256), 0, stream,
                     A, w3, b3, ws, out);
}